// Round 11
// baseline (367.074 us; speedup 1.0000x reference)
//
#include <hip/hip_runtime.h>
#include <hip/hip_fp16.h>
#include <math.h>

#define NN 50000
#define IND 128
#define NH 4
#define NE 800000
#define NT 3
#define NSLOPE 0.2f

#define TILE 64                    // dsts per bucket
#define NBPT 782                   // ceil(NN/TILE)
#define NBTOT (NT * NBPT)          // 2346
#define BCAP 1280                  // slots per bucket (Poisson λ=1024, +8σ)

#define SCB ((NT * NE + 8191) / 8192)   // 293 scatter blocks
#define CVB ((NN + 127) / 128)          // 391 conv blocks

typedef _Float16 f16x8 __attribute__((ext_vector_type(8)));
typedef float    f32x4 __attribute__((ext_vector_type(4)));

// ---------------- prep: W^T fp16, vab fused score vectors, gcursor ----------------
// vab16[c][d], c = t*4+hd (es) / c+12 (ed): = sum_dk W[t,d,hd,dk]*a[t,hd,dk]
__global__ __launch_bounds__(256) void prep_kernel(
    const float* __restrict__ W, const float* __restrict__ asrc, const float* __restrict__ adst,
    __half* __restrict__ wt16g, __half* __restrict__ vab16, int* __restrict__ gcursor)
{
    int idx = blockIdx.x * 256 + threadIdx.x;
    if (idx < NT * IND * IND) {
        int t = idx / (IND * IND), r = idx - t * (IND * IND);
        int k = r >> 7, c = r & 127;
        wt16g[((size_t)t * IND + c) * IND + k] = (__half)W[idx];   // wt16g[t][c][k=d]
    }
    if (idx < 32 * 128) {
        int c = idx >> 7, d = idx & 127;
        float acc = 0.f;
        if (c < 24) {
            int cc = c < 12 ? c : c - 12;
            int t = cc >> 2, hd = cc & 3;
            const float* wrow = W + ((size_t)(t * IND + d) * NH + hd) * 32;
            const float* av = (c < 12 ? asrc : adst) + ((size_t)t * NH + hd) * 32;
            #pragma unroll
            for (int dk = 0; dk < 32; dk++) acc = fmaf(wrow[dk], av[dk], acc);
        }
        vab16[idx] = (__half)acc;
    }
    if (idx < NBTOT) gcursor[idx] = idx * BCAP;
}

// ---------------- combined: bucket_scatter + {x->fp16 conversion, es/ed MFMA} ----------------
__global__ __launch_bounds__(512) void scatter_conv_kernel(
    const int* __restrict__ edges, int* __restrict__ gcursor, unsigned* __restrict__ bucketed,
    const float* __restrict__ x, const __half* __restrict__ vab16,
    __half* __restrict__ x16, float* __restrict__ es, float* __restrict__ ed)
{
    const int tid = threadIdx.x;

    if (blockIdx.x < SCB) {
        __shared__ int cnt[NBTOT];
        __shared__ int bas[NBTOT];
        for (int i = tid; i < NBTOT; i += 512) cnt[i] = 0;
        __syncthreads();
        const long long gtot = (long long)NT * NE;
        const long long g0 = (long long)blockIdx.x * 8192;
        long long g1 = g0 + 8192; if (g1 > gtot) g1 = gtot;
        for (long long g = g0 + tid; g < g1; g += 512) {
            int t = (g >= 2LL * NE) ? 2 : (g >= NE ? 1 : 0);
            int e = (int)(g - (long long)t * NE);
            int d = edges[(size_t)t * 2 * NE + NE + e];
            atomicAdd(&cnt[t * NBPT + (d >> 6)], 1);
        }
        __syncthreads();
        for (int i = tid; i < NBTOT; i += 512) {
            int c = cnt[i];
            bas[i] = c ? atomicAdd(&gcursor[i], c) : 0;
            cnt[i] = 0;
        }
        __syncthreads();
        for (long long g = g0 + tid; g < g1; g += 512) {
            int t = (g >= 2LL * NE) ? 2 : (g >= NE ? 1 : 0);
            int e = (int)(g - (long long)t * NE);
            const int* eb = edges + (size_t)t * 2 * NE;
            int s = eb[e], d = eb[NE + e];
            int bg = t * NBPT + (d >> 6);
            int pos = bas[bg] + atomicAdd(&cnt[bg], 1);
            bucketed[pos] = (unsigned)s | ((unsigned)(d & 63) << 16);
        }
        return;
    }

    // ---- conv: 8 waves x 16 rows = 128 rows/block ----
    const int bx = blockIdx.x - SCB;
    const int wid = tid >> 6, lane = tid & 63;
    const int l15 = lane & 15, l4 = lane >> 4;
    const int r0 = bx * 128 + wid * 16;
    if (r0 >= NN) return;                       // NN%16==0 -> wave-uniform

    const float* xrow = x + (size_t)(r0 + l15) * IND;
    __half* x16row = x16 + (size_t)(r0 + l15) * IND;

    f32x4 acc0 = {0.f,0.f,0.f,0.f}, acc1 = {0.f,0.f,0.f,0.f};
    #pragma unroll
    for (int ks = 0; ks < 4; ks++) {
        const int kb = ks * 32 + l4 * 8;
        float4 a = *reinterpret_cast<const float4*>(xrow + kb);
        float4 b = *reinterpret_cast<const float4*>(xrow + kb + 4);
        f16x8 af;
        af[0] = (_Float16)a.x; af[1] = (_Float16)a.y;
        af[2] = (_Float16)a.z; af[3] = (_Float16)a.w;
        af[4] = (_Float16)b.x; af[5] = (_Float16)b.y;
        af[6] = (_Float16)b.z; af[7] = (_Float16)b.w;
        *reinterpret_cast<f16x8*>(x16row + kb) = af;
        f16x8 b0 = *reinterpret_cast<const f16x8*>((const __half*)vab16 + (size_t)l15 * IND + kb);
        f16x8 b1 = *reinterpret_cast<const f16x8*>((const __half*)vab16 + (size_t)(16 + l15) * IND + kb);
        acc0 = __builtin_amdgcn_mfma_f32_16x16x32_f16(af, b0, acc0, 0, 0, 0);
        acc1 = __builtin_amdgcn_mfma_f32_16x16x32_f16(af, b1, acc1, 0, 0, 0);
    }
    // D: row=l4*4+r, col=l15 (acc0 cols: es[0..11], ed[0..3]; acc1 cols 16..23: ed[4..11])
    #pragma unroll
    for (int r = 0; r < 4; r++) {
        int n = r0 + l4 * 4 + r;
        float v0 = acc0[r], v1 = acc1[r];
        if (l15 < 12) {
            es[((size_t)(l15 >> 2) * NN + n) * NH + (l15 & 3)] = v0;
        } else {
            int cc = l15 - 12;
            ed[((size_t)(cc >> 2) * NN + n) * NH + (cc & 3)] = v0;
        }
        if (l15 < 8) {
            int cc = l15 + 4;
            ed[((size_t)(cc >> 2) * NN + n) * NH + (cc & 3)] = v1;
        }
    }
}

// ---------------- per-bucket (one type): sort -> per-head weighted x-aggregation ----------------
// Lane role: hd = lane>>4 (output head), dl3 = lane&15 (dims 8*dl3..+7).
// G[n][hd][d] = sum_e w_e^{hd} * x16[src_e][d] / sum_e w_e^{hd}.
// Edge loop is fully divergence-free (uniform bounds, unconditional shuffles/loads).
__global__ __launch_bounds__(512) void gat_gather_kernel(
    const unsigned* __restrict__ bucketed, const int* __restrict__ gcursor,
    const float* __restrict__ es_t, const float* __restrict__ ed_t,
    const __half* __restrict__ x16, __half* __restrict__ g16, int tbase)
{
    __shared__ unsigned pk[BCAP];
    __shared__ unsigned srt[BCAP];
    __shared__ int hist[TILE], scn[TILE], cur[TILE];
    const int bg = tbase + blockIdx.x;
    const int node0 = blockIdx.x * TILE;
    const int tid = threadIdx.x;
    const int base = bg * BCAP;
    const int cnt = gcursor[bg] - base;

    if (tid < TILE) { hist[tid] = 0; cur[tid] = 0; }
    __syncthreads();
    for (int i = tid; i < cnt; i += 512) {
        unsigned v = bucketed[base + i];
        pk[i] = v;
        atomicAdd(&hist[(v >> 16) & 63u], 1);
    }
    __syncthreads();
    if (tid < 64) {
        int v = hist[tid];
        int inc = v;
        #pragma unroll
        for (int off = 1; off < 64; off <<= 1) {
            int n = __shfl_up(inc, off, 64);
            if (tid >= off) inc += n;
        }
        scn[tid] = inc - v;
    }
    __syncthreads();
    for (int i = tid; i < cnt; i += 512) {
        unsigned v = pk[i];
        int dl = (int)((v >> 16) & 63u);
        int pos = scn[dl] + atomicAdd(&cur[dl], 1);
        srt[pos] = v & 0xFFFFu;
    }
    __syncthreads();

    const int wid = tid >> 6, lane = tid & 63;
    const int hd  = lane >> 4;         // output head owned by this lane
    const int dl3 = lane & 15;         // input dims 8*dl3..8*dl3+7

    for (int j = 0; j < 8; j++) {
        const int dloc = wid * 8 + j;
        const int node = node0 + dloc;
        if (node >= NN) break;
        const int beg = scn[dloc], nE = hist[dloc];
        const float edv = ed_t[(size_t)node * NH + (lane & 3)];

        float a0=0.f,a1=0.f,a2=0.f,a3=0.f,a4=0.f,a5=0.f,a6=0.f,a7=0.f,dsum=0.f;

        for (int b2 = 0; b2 < nE; b2 += 16) {
            int ne = nE - b2; if (ne > 16) ne = 16;
            const int ei = lane >> 2;
            float wv = 0.f; int sv = 0;
            if (ei < ne) {
                sv = (int)srt[beg + b2 + ei];
                float s = es_t[(sv << 2) + (lane & 3)] + edv;
                s = s > 0.f ? s : NSLOPE * s;
                wv = __expf(s);
                dsum += wv;
            }
            for (int k = 0; k < ne; k++) {       // uniform bound, no divergence
                int   sb = __shfl(sv, k << 2, 64);
                float wb = __shfl(wv, (k << 2) | hd, 64);
                uint4 hv = *reinterpret_cast<const uint4*>(x16 + ((size_t)sb << 7) + (dl3 << 3));
                asm("v_fma_mix_f32 %0, %1, %2, %0 op_sel:[0,0,0] op_sel_hi:[1,0,0]" : "+v"(a0) : "v"(hv.x), "v"(wb));
                asm("v_fma_mix_f32 %0, %1, %2, %0 op_sel:[1,0,0] op_sel_hi:[1,0,0]" : "+v"(a1) : "v"(hv.x), "v"(wb));
                asm("v_fma_mix_f32 %0, %1, %2, %0 op_sel:[0,0,0] op_sel_hi:[1,0,0]" : "+v"(a2) : "v"(hv.y), "v"(wb));
                asm("v_fma_mix_f32 %0, %1, %2, %0 op_sel:[1,0,0] op_sel_hi:[1,0,0]" : "+v"(a3) : "v"(hv.y), "v"(wb));
                asm("v_fma_mix_f32 %0, %1, %2, %0 op_sel:[0,0,0] op_sel_hi:[1,0,0]" : "+v"(a4) : "v"(hv.z), "v"(wb));
                asm("v_fma_mix_f32 %0, %1, %2, %0 op_sel:[1,0,0] op_sel_hi:[1,0,0]" : "+v"(a5) : "v"(hv.z), "v"(wb));
                asm("v_fma_mix_f32 %0, %1, %2, %0 op_sel:[0,0,0] op_sel_hi:[1,0,0]" : "+v"(a6) : "v"(hv.w), "v"(wb));
                asm("v_fma_mix_f32 %0, %1, %2, %0 op_sel:[1,0,0] op_sel_hi:[1,0,0]" : "+v"(a7) : "v"(hv.w), "v"(wb));
            }
        }

        #pragma unroll
        for (int m = 4; m <= 32; m <<= 1) dsum += __shfl_xor(dsum, m, 64);
        float rn = 1.f / (__shfl(dsum, hd, 64) + 1e-9f);

        f16x8 g;
        g[0] = (_Float16)(a0 * rn); g[1] = (_Float16)(a1 * rn);
        g[2] = (_Float16)(a2 * rn); g[3] = (_Float16)(a3 * rn);
        g[4] = (_Float16)(a4 * rn); g[5] = (_Float16)(a5 * rn);
        g[6] = (_Float16)(a6 * rn); g[7] = (_Float16)(a7 * rn);
        // offset = hd*128 + dl3*8 == lane*8 -> 64 lanes write 1KB contiguous
        *reinterpret_cast<f16x8*>(g16 + (size_t)node * 512 + lane * 8) = g;
    }
}

// ---------------- out = elu(G[hd] @ W[:,hd,:]) per type, dual nontemporal write ----------------
// 4 waves x 16 nodes; A-fragment per head: af[hd] from g16[n][hd][d]; B = wt16g[t][c][d].
__global__ __launch_bounds__(256) void out_gemm_kernel(
    const __half* __restrict__ g16, const __half* __restrict__ wt,
    float* __restrict__ outa, float* __restrict__ outb)
{
    const int tid = threadIdx.x;
    const int wid = tid >> 6, lane = tid & 63;
    const int l15 = lane & 15, l4 = lane >> 4;
    const int n0 = blockIdx.x * 64 + wid * 16;
    if (n0 >= NN) return;                       // NN%16==0 -> wave-uniform

    const __half* grow = g16 + (size_t)(n0 + l15) * 512;

    f32x4 acc[8];
    #pragma unroll
    for (int i = 0; i < 8; i++) acc[i] = (f32x4){0.f,0.f,0.f,0.f};

    #pragma unroll
    for (int ks = 0; ks < 4; ks++) {
        const int kb = ks * 32 + l4 * 8;
        f16x8 af0 = *reinterpret_cast<const f16x8*>(grow + 0 * IND + kb);
        f16x8 af1 = *reinterpret_cast<const f16x8*>(grow + 1 * IND + kb);
        f16x8 af2 = *reinterpret_cast<const f16x8*>(grow + 2 * IND + kb);
        f16x8 af3 = *reinterpret_cast<const f16x8*>(grow + 3 * IND + kb);
        #pragma unroll
        for (int ct = 0; ct < 8; ct++) {
            f16x8 bf = *reinterpret_cast<const f16x8*>(wt + (size_t)(ct * 16 + l15) * IND + kb);
            f16x8 af = (ct < 2) ? af0 : (ct < 4) ? af1 : (ct < 6) ? af2 : af3;
            acc[ct] = __builtin_amdgcn_mfma_f32_16x16x32_f16(af, bf, acc[ct], 0, 0, 0);
        }
    }

    #pragma unroll
    for (int ct = 0; ct < 8; ct++) {
        #pragma unroll
        for (int r = 0; r < 4; r++) {
            int n = n0 + l4 * 4 + r;
            float v = acc[ct][r];
            float o = v > 0.f ? v : expm1f(v);
            size_t off = (size_t)n * IND + ct * 16 + l15;
            __builtin_nontemporal_store(o, outa + off);
            __builtin_nontemporal_store(o, outb + off);
        }
    }
}

extern "C" void kernel_launch(void* const* d_in, const int* in_sizes, int n_in,
                              void* d_out, int out_size, void* d_ws, size_t ws_size,
                              hipStream_t stream)
{
    const float* x     = (const float*)d_in[0];
    const int*   edges = (const int*)d_in[1];
    const float* W     = (const float*)d_in[2];
    const float* asrc  = (const float*)d_in[3];
    const float* adst  = (const float*)d_in[4];
    float* out = (float*)d_out;

    char* p = (char*)d_ws;
    __half*   x16      = (__half*)p;   p += (size_t)NN * IND * 2;                 // 12.8 MB
    __half*   g16      = (__half*)p;   p += (size_t)NN * 512 * 2;                 // 51.2 MB (per-type)
    float*    es       = (float*)p;    p += (size_t)NT * NN * NH * 4;             // 2.4 MB
    float*    ed       = (float*)p;    p += (size_t)NT * NN * NH * 4;             // 2.4 MB
    int*      gcursor  = (int*)p;      p += (size_t)NBTOT * 4;
    __half*   wt16g    = (__half*)p;   p += (size_t)NT * IND * IND * 2;           // 96 KB
    __half*   vab16    = (__half*)p;   p += (size_t)32 * IND * 2;                 // 8 KB
    unsigned* bucketed = (unsigned*)p; p += ((size_t)NBTOT * BCAP + 1024) * 4;    // 12 MB

    prep_kernel<<<(NT * IND * IND + 255) / 256, 256, 0, stream>>>(
        W, asrc, adst, wt16g, vab16, gcursor);
    scatter_conv_kernel<<<SCB + CVB, 512, 0, stream>>>(
        edges, gcursor, bucketed, x, vab16, x16, es, ed);

    for (int t = 0; t < NT; t++) {
        gat_gather_kernel<<<NBPT, 512, 0, stream>>>(
            bucketed, gcursor,
            es + (size_t)t * NN * NH, ed + (size_t)t * NN * NH,
            x16, g16, t * NBPT);
        out_gemm_kernel<<<(NN + 63) / 64, 256, 0, stream>>>(
            g16, wt16g + (size_t)t * IND * IND,
            out + (size_t)t * NN * IND, out + (size_t)(NT + t) * NN * IND);
    }
}